// Round 1
// baseline (554.029 us; speedup 1.0000x reference)
//
#include <hip/hip_runtime.h>

typedef __bf16 bf16x8 __attribute__((ext_vector_type(8)));
typedef float  f32x4  __attribute__((ext_vector_type(4)));

__device__ __forceinline__ unsigned short f2bf(float f) {
  unsigned u = __builtin_bit_cast(unsigned, f);
  u += 0x7FFFu + ((u >> 16) & 1u);          // round-to-nearest-even
  return (unsigned short)(u >> 16);
}
__device__ __forceinline__ float bf2f(unsigned short b) {
  unsigned u = ((unsigned)b) << 16;
  return __builtin_bit_cast(float, u);
}

__device__ __forceinline__ void gload_lds16(const void* g, void* l) {
  __builtin_amdgcn_global_load_lds(
      (const __attribute__((address_space(1))) unsigned int*)g,
      (__attribute__((address_space(3))) unsigned int*)l, 16, 0, 0);
}

// ---------------- prep: W -> Wt (transposed bf16), zero stats ----------------
__global__ __launch_bounds__(256) void prep_kernel(
    const float* __restrict__ W1, const float* __restrict__ W2,
    unsigned short* __restrict__ Wt1, unsigned short* __restrict__ Wt2,
    float* __restrict__ stats)
{
  const int n = blockIdx.x;    // output row (original column)
  const int k = threadIdx.x;
  Wt1[n * 256 + k] = f2bf(W1[k * 256 + n]);
  Wt2[n * 256 + k] = f2bf(W2[k * 256 + n]);
  if (n == 0) { stats[k] = 0.f; stats[256 + k] = 0.f; }
}

// ---------------- aggregate: h0 = mean over neighbors of x ----------------
__global__ __launch_bounds__(256) void aggregate_kernel(
    const float* __restrict__ x, const int* __restrict__ nbr,
    unsigned short* __restrict__ h0, int N)
{
  const int gw   = (blockIdx.x * 256 + threadIdx.x) >> 6;  // node id (wave/node)
  const int lane = threadIdx.x & 63;
  if (gw >= N) return;
  const int* nb = nbr + (long)gw * 16;
  float4 s = make_float4(0.f, 0.f, 0.f, 0.f);
  int deg = 0;
#pragma unroll
  for (int j = 0; j < 16; ++j) {
    int v = nb[j];
    if (v >= 0) {
      float4 t = ((const float4*)(x + (long)v * 256))[lane];
      s.x += t.x; s.y += t.y; s.z += t.z; s.w += t.w;
      deg++;
    }
  }
  float inv = deg > 0 ? 1.0f / (float)deg : 0.f;
  ushort4 o;
  o.x = f2bf(s.x * inv); o.y = f2bf(s.y * inv);
  o.z = f2bf(s.z * inv); o.w = f2bf(s.w * inv);
  ((ushort4*)(h0 + (long)gw * 256))[lane] = o;
}

// ------- combine: h1 = h0 + alpha*maxpool(h0, nbrs) + (1+eps)*x -------------
__global__ __launch_bounds__(256) void combine_kernel(
    const unsigned short* __restrict__ h0, const int* __restrict__ nbr,
    const float* __restrict__ x, const float* __restrict__ alpha_p,
    const float* __restrict__ eps_p, unsigned short* __restrict__ h1, int N)
{
  const int gw   = (blockIdx.x * 256 + threadIdx.x) >> 6;
  const int lane = threadIdx.x & 63;
  if (gw >= N) return;
  const float alpha = *alpha_p;
  const float c     = 1.0f + *eps_p;
  const int* nb = nbr + (long)gw * 16;
  float4 mx = make_float4(-3.402823466e38f, -3.402823466e38f,
                          -3.402823466e38f, -3.402823466e38f);
#pragma unroll
  for (int j = 0; j < 16; ++j) {
    int v = nb[j];
    if (v >= 0) {
      ushort4 t = ((const ushort4*)(h0 + (long)v * 256))[lane];
      mx.x = fmaxf(mx.x, bf2f(t.x)); mx.y = fmaxf(mx.y, bf2f(t.y));
      mx.z = fmaxf(mx.z, bf2f(t.z)); mx.w = fmaxf(mx.w, bf2f(t.w));
    }
  }
  ushort4 own = ((const ushort4*)(h0 + (long)gw * 256))[lane];
  float4  xv  = ((const float4*)(x + (long)gw * 256))[lane];
  ushort4 o;
  o.x = f2bf(bf2f(own.x) + alpha * mx.x + c * xv.x);
  o.y = f2bf(bf2f(own.y) + alpha * mx.y + c * xv.y);
  o.z = f2bf(bf2f(own.z) + alpha * mx.z + c * xv.z);
  o.w = f2bf(bf2f(own.w) + alpha * mx.w + c * xv.w);
  ((ushort4*)(h1 + (long)gw * 256))[lane] = o;
}

// ---------------- GEMM + bias + relu (+ optional BN stats) ------------------
// C[M][256] = relu(A[M][256] @ W[256][256] + b); A bf16, Wt = W^T bf16 [n][k].
// 128x128 tile, BK=32, 4 waves (2x2), 16x16x32 bf16 MFMA.
template<int WITH_STATS>
__global__ __launch_bounds__(256, 2) void gemm_relu_kernel(
    const unsigned short* __restrict__ A, const unsigned short* __restrict__ Wt,
    const float* __restrict__ bias, unsigned short* __restrict__ Out,
    float* __restrict__ stats, int M)
{
  __shared__ __align__(16) unsigned short lA[128 * 32];
  __shared__ __align__(16) unsigned short lB[128 * 32];
  const int tid  = threadIdx.x;
  const int lane = tid & 63;
  const int wave = tid >> 6;
  const int wm = wave >> 1, wn = wave & 1;
  const int g = lane >> 4, lr = lane & 15;
  const long row0 = (long)blockIdx.x * 128;
  const int  col0 = blockIdx.y * 128;

  f32x4 acc[4][4] = {};

  // staging geometry: two rounds of 256 lanes x 16B cover 128 rows x 64B
  const int o0 = tid * 16;
  const int o1 = (256 + tid) * 16;
  const int ra = o0 >> 6, ca = o0 & 63;
  const int rb = o1 >> 6, cb = o1 & 63;
  const char* Ab = (const char*)A;
  const char* Bb = (const char*)Wt;
  char* lAc = (char*)lA;
  char* lBc = (char*)lB;

  for (int kk = 0; kk < 8; ++kk) {
    const int kb = kk * 64;   // byte offset in K
    gload_lds16(Ab + (row0 + ra) * 512 + kb + ca, lAc + wave * 1024);
    gload_lds16(Ab + (row0 + rb) * 512 + kb + cb, lAc + 4096 + wave * 1024);
    gload_lds16(Bb + (long)(col0 + ra) * 512 + kb + ca, lBc + wave * 1024);
    gload_lds16(Bb + (long)(col0 + rb) * 512 + kb + cb, lBc + 4096 + wave * 1024);
    __syncthreads();
    bf16x8 af[4], bq[4];
#pragma unroll
    for (int mt = 0; mt < 4; ++mt)
      af[mt] = *(const bf16x8*)&lA[(wm * 64 + mt * 16 + lr) * 32 + 8 * g];
#pragma unroll
    for (int nt = 0; nt < 4; ++nt)
      bq[nt] = *(const bf16x8*)&lB[(wn * 64 + nt * 16 + lr) * 32 + 8 * g];
#pragma unroll
    for (int mt = 0; mt < 4; ++mt)
#pragma unroll
      for (int nt = 0; nt < 4; ++nt)
        acc[mt][nt] = __builtin_amdgcn_mfma_f32_16x16x32_bf16(
            af[mt], bq[nt], acc[mt][nt], 0, 0, 0);
    __syncthreads();
  }

  // epilogue: bias + relu + store bf16 (+ column stats)
#pragma unroll
  for (int nt = 0; nt < 4; ++nt) {
    const int col = col0 + wn * 64 + nt * 16 + lr;
    const float bv = bias[col];
    float s = 0.f, s2 = 0.f;
#pragma unroll
    for (int mt = 0; mt < 4; ++mt) {
      const long rbase = row0 + wm * 64 + mt * 16 + g * 4;
      f32x4 v = acc[mt][nt];
#pragma unroll
      for (int r = 0; r < 4; ++r) {
        float val = fmaxf(v[r] + bv, 0.f);
        const long row = rbase + r;
        if (row < M) {
          Out[row * 256 + col] = f2bf(val);
          if (WITH_STATS) { s += val; s2 += val * val; }
        }
      }
    }
    if (WITH_STATS) {
      s  += __shfl_xor(s, 16);  s2 += __shfl_xor(s2, 16);
      s  += __shfl_xor(s, 32);  s2 += __shfl_xor(s2, 32);
      if (g == 0) {
        atomicAdd(&stats[col], s);
        atomicAdd(&stats[256 + col], s2);
      }
    }
  }
}

// ---------------- BN finalize: scale/shift per column -----------------------
__global__ __launch_bounds__(256) void bn_finalize_kernel(
    const float* __restrict__ gamma, const float* __restrict__ beta,
    float* __restrict__ stats, int M)
{
  const int n = threadIdx.x;
  const float invM = 1.0f / (float)M;
  const float mean = stats[n] * invM;
  float var = stats[256 + n] * invM - mean * mean;
  var = fmaxf(var, 0.f);
  const float sc = gamma[n] * rsqrtf(var + 1e-5f);
  stats[512 + n] = sc;
  stats[768 + n] = beta[n] - mean * sc;
}

// ---------------- BN normalize: out = h3*scale + shift ----------------------
__global__ __launch_bounds__(256) void bn_norm_kernel(
    const unsigned short* __restrict__ h3, const float* __restrict__ stats,
    float* __restrict__ out, int total4)
{
  const int i = blockIdx.x * 256 + threadIdx.x;
  if (i >= total4) return;
  ushort4 v = ((const ushort4*)h3)[i];
  const int c = (i * 4) & 255;
  const float4 sc = *(const float4*)&stats[512 + c];
  const float4 sh = *(const float4*)&stats[768 + c];
  float4 o;
  o.x = bf2f(v.x) * sc.x + sh.x;
  o.y = bf2f(v.y) * sc.y + sh.y;
  o.z = bf2f(v.z) * sc.z + sh.z;
  o.w = bf2f(v.w) * sc.w + sh.w;
  ((float4*)out)[i] = o;
}

// ----------------------------------------------------------------------------
extern "C" void kernel_launch(void* const* d_in, const int* in_sizes, int n_in,
                              void* d_out, int out_size, void* d_ws, size_t ws_size,
                              hipStream_t stream) {
  const float* x     = (const float*)d_in[0];
  const int*   nbr   = (const int*)d_in[1];
  const float* W1    = (const float*)d_in[2];
  const float* b1    = (const float*)d_in[3];
  const float* W2    = (const float*)d_in[4];
  const float* b2    = (const float*)d_in[5];
  const float* gamma = (const float*)d_in[6];
  const float* beta  = (const float*)d_in[7];
  const float* alpha_p = (const float*)d_in[8];
  const float* eps_p   = (const float*)d_in[9];
  float* out = (float*)d_out;

  const int  N  = in_sizes[0] / 256;            // 100000
  const long MP = ((long)N + 127) & ~127L;      // padded rows for GEMM tiles

  unsigned short* bufA = (unsigned short*)d_ws;     // h0, then h2
  unsigned short* bufB = bufA + MP * 256;           // h1, then h3
  unsigned short* Wt1  = bufB + MP * 256;
  unsigned short* Wt2  = Wt1 + 256 * 256;
  float* stats = (float*)(Wt2 + 256 * 256);         // sum|sumsq|scale|shift

  prep_kernel<<<256, 256, 0, stream>>>(W1, W2, Wt1, Wt2, stats);
  aggregate_kernel<<<(N + 3) / 4, 256, 0, stream>>>(x, nbr, bufA, N);
  combine_kernel<<<(N + 3) / 4, 256, 0, stream>>>(bufA, nbr, x, alpha_p, eps_p, bufB, N);

  dim3 ggrid((unsigned)((N + 127) / 128), 2);
  gemm_relu_kernel<0><<<ggrid, 256, 0, stream>>>(bufB, Wt1, b1, bufA, nullptr, N);
  gemm_relu_kernel<1><<<ggrid, 256, 0, stream>>>(bufA, Wt2, b2, bufB, stats, N);

  bn_finalize_kernel<<<1, 256, 0, stream>>>(gamma, beta, stats, N);
  bn_norm_kernel<<<(N * 64 + 255) / 256, 256, 0, stream>>>(bufB, stats, out, N * 64);
}

// Round 2
// 507.936 us; speedup vs baseline: 1.0907x; 1.0907x over previous
//
#include <hip/hip_runtime.h>

typedef __bf16 bf16x8 __attribute__((ext_vector_type(8)));
typedef float  f32x4  __attribute__((ext_vector_type(4)));

__device__ __forceinline__ unsigned short f2bf(float f) {
  unsigned u = __builtin_bit_cast(unsigned, f);
  u += 0x7FFFu + ((u >> 16) & 1u);          // round-to-nearest-even
  return (unsigned short)(u >> 16);
}
__device__ __forceinline__ float bf2f(unsigned short b) {
  unsigned u = ((unsigned)b) << 16;
  return __builtin_bit_cast(float, u);
}

__device__ __forceinline__ void gload_lds16(const void* g, void* l) {
  __builtin_amdgcn_global_load_lds(
      (const __attribute__((address_space(1))) unsigned int*)g,
      (__attribute__((address_space(3))) unsigned int*)l, 16, 0, 0);
}

// ---------------- x -> bf16 copy (gather source) ----------------------------
__global__ __launch_bounds__(256) void x2bf_kernel(
    const float* __restrict__ x, unsigned short* __restrict__ xh, int total8)
{
  const int i = blockIdx.x * 256 + threadIdx.x;
  if (i >= total8) return;
  const float4* p = (const float4*)x + (long)i * 2;
  float4 a = p[0], b = p[1];
  ushort4 o0, o1;
  o0.x = f2bf(a.x); o0.y = f2bf(a.y); o0.z = f2bf(a.z); o0.w = f2bf(a.w);
  o1.x = f2bf(b.x); o1.y = f2bf(b.y); o1.z = f2bf(b.z); o1.w = f2bf(b.w);
  ushort4* q = (ushort4*)xh + (long)i * 2;
  q[0] = o0; q[1] = o1;
}

// ---------------- prep: W -> Wt (transposed bf16), zero stats ----------------
__global__ __launch_bounds__(256) void prep_kernel(
    const float* __restrict__ W1, const float* __restrict__ W2,
    unsigned short* __restrict__ Wt1, unsigned short* __restrict__ Wt2,
    float* __restrict__ stats)
{
  const int n = blockIdx.x;    // output row (original column)
  const int k = threadIdx.x;
  Wt1[n * 256 + k] = f2bf(W1[k * 256 + n]);
  Wt2[n * 256 + k] = f2bf(W2[k * 256 + n]);
  if (n == 0) { stats[k] = 0.f; stats[256 + k] = 0.f; }
}

// ---------------- aggregate: h0 = mean over neighbors of xh (bf16) ----------
__global__ __launch_bounds__(256) void aggregate_kernel(
    const unsigned short* __restrict__ xh, const int* __restrict__ nbr,
    unsigned short* __restrict__ h0, int N)
{
  const int gw   = (blockIdx.x * 256 + threadIdx.x) >> 6;  // node id (wave/node)
  const int lane = threadIdx.x & 63;
  if (gw >= N) return;
  const int* nb = nbr + (long)gw * 16;
  float4 s = make_float4(0.f, 0.f, 0.f, 0.f);
  int deg = 0;
#pragma unroll
  for (int j = 0; j < 16; ++j) {
    int v = nb[j];
    if (v >= 0) {
      ushort4 t = ((const ushort4*)(xh + (long)v * 256))[lane];
      s.x += bf2f(t.x); s.y += bf2f(t.y);
      s.z += bf2f(t.z); s.w += bf2f(t.w);
      deg++;
    }
  }
  float inv = deg > 0 ? 1.0f / (float)deg : 0.f;
  ushort4 o;
  o.x = f2bf(s.x * inv); o.y = f2bf(s.y * inv);
  o.z = f2bf(s.z * inv); o.w = f2bf(s.w * inv);
  ((ushort4*)(h0 + (long)gw * 256))[lane] = o;
}

// ------- combine: h1 = h0 + alpha*maxpool(h0, nbrs) + (1+eps)*x -------------
__global__ __launch_bounds__(256) void combine_kernel(
    const unsigned short* __restrict__ h0, const int* __restrict__ nbr,
    const unsigned short* __restrict__ xh, const float* __restrict__ alpha_p,
    const float* __restrict__ eps_p, unsigned short* __restrict__ h1, int N)
{
  const int gw   = (blockIdx.x * 256 + threadIdx.x) >> 6;
  const int lane = threadIdx.x & 63;
  if (gw >= N) return;
  const float alpha = *alpha_p;
  const float c     = 1.0f + *eps_p;
  const int* nb = nbr + (long)gw * 16;
  float4 mx = make_float4(-3.402823466e38f, -3.402823466e38f,
                          -3.402823466e38f, -3.402823466e38f);
#pragma unroll
  for (int j = 0; j < 16; ++j) {
    int v = nb[j];
    if (v >= 0) {
      ushort4 t = ((const ushort4*)(h0 + (long)v * 256))[lane];
      mx.x = fmaxf(mx.x, bf2f(t.x)); mx.y = fmaxf(mx.y, bf2f(t.y));
      mx.z = fmaxf(mx.z, bf2f(t.z)); mx.w = fmaxf(mx.w, bf2f(t.w));
    }
  }
  ushort4 own = ((const ushort4*)(h0 + (long)gw * 256))[lane];
  ushort4 xv  = ((const ushort4*)(xh + (long)gw * 256))[lane];
  ushort4 o;
  o.x = f2bf(bf2f(own.x) + alpha * mx.x + c * bf2f(xv.x));
  o.y = f2bf(bf2f(own.y) + alpha * mx.y + c * bf2f(xv.y));
  o.z = f2bf(bf2f(own.z) + alpha * mx.z + c * bf2f(xv.z));
  o.w = f2bf(bf2f(own.w) + alpha * mx.w + c * bf2f(xv.w));
  ((ushort4*)(h1 + (long)gw * 256))[lane] = o;
}

// ---------------- GEMM + bias + relu (+ optional BN stats) ------------------
// C[M][256] = relu(A[M][256] @ W[256][256] + b); A bf16, Wt = W^T bf16 [n][k].
// 128x128 tile, BK=32, 4 waves (2x2), 16x16x32 bf16 MFMA.
template<int WITH_STATS>
__global__ __launch_bounds__(256, 2) void gemm_relu_kernel(
    const unsigned short* __restrict__ A, const unsigned short* __restrict__ Wt,
    const float* __restrict__ bias, unsigned short* __restrict__ Out,
    float* __restrict__ stats, int M)
{
  __shared__ __align__(16) unsigned short lA[128 * 32];
  __shared__ __align__(16) unsigned short lB[128 * 32];
  const int tid  = threadIdx.x;
  const int lane = tid & 63;
  const int wave = tid >> 6;
  const int wm = wave >> 1, wn = wave & 1;
  const int g = lane >> 4, lr = lane & 15;
  const long row0 = (long)blockIdx.x * 128;
  const int  col0 = blockIdx.y * 128;

  f32x4 acc[4][4] = {};

  // staging geometry: two rounds of 256 lanes x 16B cover 128 rows x 64B
  const int o0 = tid * 16;
  const int o1 = (256 + tid) * 16;
  const int ra = o0 >> 6, ca = o0 & 63;
  const int rb = o1 >> 6, cb = o1 & 63;
  const char* Ab = (const char*)A;
  const char* Bb = (const char*)Wt;
  char* lAc = (char*)lA;
  char* lBc = (char*)lB;

  for (int kk = 0; kk < 8; ++kk) {
    const int kb = kk * 64;   // byte offset in K
    gload_lds16(Ab + (row0 + ra) * 512 + kb + ca, lAc + wave * 1024);
    gload_lds16(Ab + (row0 + rb) * 512 + kb + cb, lAc + 4096 + wave * 1024);
    gload_lds16(Bb + (long)(col0 + ra) * 512 + kb + ca, lBc + wave * 1024);
    gload_lds16(Bb + (long)(col0 + rb) * 512 + kb + cb, lBc + 4096 + wave * 1024);
    __syncthreads();
    bf16x8 af[4], bq[4];
#pragma unroll
    for (int mt = 0; mt < 4; ++mt)
      af[mt] = *(const bf16x8*)&lA[(wm * 64 + mt * 16 + lr) * 32 + 8 * g];
#pragma unroll
    for (int nt = 0; nt < 4; ++nt)
      bq[nt] = *(const bf16x8*)&lB[(wn * 64 + nt * 16 + lr) * 32 + 8 * g];
#pragma unroll
    for (int mt = 0; mt < 4; ++mt)
#pragma unroll
      for (int nt = 0; nt < 4; ++nt)
        acc[mt][nt] = __builtin_amdgcn_mfma_f32_16x16x32_bf16(
            af[mt], bq[nt], acc[mt][nt], 0, 0, 0);
    __syncthreads();
  }

  // epilogue: bias + relu + store bf16 (+ column stats)
#pragma unroll
  for (int nt = 0; nt < 4; ++nt) {
    const int col = col0 + wn * 64 + nt * 16 + lr;
    const float bv = bias[col];
    float s = 0.f, s2 = 0.f;
#pragma unroll
    for (int mt = 0; mt < 4; ++mt) {
      const long rbase = row0 + wm * 64 + mt * 16 + g * 4;
      f32x4 v = acc[mt][nt];
#pragma unroll
      for (int r = 0; r < 4; ++r) {
        float val = fmaxf(v[r] + bv, 0.f);
        const long row = rbase + r;
        if (row < M) {
          Out[row * 256 + col] = f2bf(val);
          if (WITH_STATS) { s += val; s2 += val * val; }
        }
      }
    }
    if (WITH_STATS) {
      s  += __shfl_xor(s, 16);  s2 += __shfl_xor(s2, 16);
      s  += __shfl_xor(s, 32);  s2 += __shfl_xor(s2, 32);
      if (g == 0) {
        atomicAdd(&stats[col], s);
        atomicAdd(&stats[256 + col], s2);
      }
    }
  }
}

// ---------------- BN finalize: scale/shift per column -----------------------
__global__ __launch_bounds__(256) void bn_finalize_kernel(
    const float* __restrict__ gamma, const float* __restrict__ beta,
    float* __restrict__ stats, int M)
{
  const int n = threadIdx.x;
  const float invM = 1.0f / (float)M;
  const float mean = stats[n] * invM;
  float var = stats[256 + n] * invM - mean * mean;
  var = fmaxf(var, 0.f);
  const float sc = gamma[n] * rsqrtf(var + 1e-5f);
  stats[512 + n] = sc;
  stats[768 + n] = beta[n] - mean * sc;
}

// ---------------- BN normalize: out = h3*scale + shift ----------------------
__global__ __launch_bounds__(256) void bn_norm_kernel(
    const unsigned short* __restrict__ h3, const float* __restrict__ stats,
    float* __restrict__ out, int total4)
{
  const int i = blockIdx.x * 256 + threadIdx.x;
  if (i >= total4) return;
  ushort4 v = ((const ushort4*)h3)[i];
  const int c = (i * 4) & 255;
  const float4 sc = *(const float4*)&stats[512 + c];
  const float4 sh = *(const float4*)&stats[768 + c];
  float4 o;
  o.x = bf2f(v.x) * sc.x + sh.x;
  o.y = bf2f(v.y) * sc.y + sh.y;
  o.z = bf2f(v.z) * sc.z + sh.z;
  o.w = bf2f(v.w) * sc.w + sh.w;
  ((float4*)out)[i] = o;
}

// ----------------------------------------------------------------------------
extern "C" void kernel_launch(void* const* d_in, const int* in_sizes, int n_in,
                              void* d_out, int out_size, void* d_ws, size_t ws_size,
                              hipStream_t stream) {
  const float* x     = (const float*)d_in[0];
  const int*   nbr   = (const int*)d_in[1];
  const float* W1    = (const float*)d_in[2];
  const float* b1    = (const float*)d_in[3];
  const float* W2    = (const float*)d_in[4];
  const float* b2    = (const float*)d_in[5];
  const float* gamma = (const float*)d_in[6];
  const float* beta  = (const float*)d_in[7];
  const float* alpha_p = (const float*)d_in[8];
  const float* eps_p   = (const float*)d_in[9];
  float* out = (float*)d_out;

  const int  N  = in_sizes[0] / 256;            // 100000
  const long MP = ((long)N + 127) & ~127L;      // padded rows for GEMM tiles

  // ws layout: xh | bufA | bufB | Wt1 | Wt2 | stats
  // lifetime: xh (x bf16) dead after combine -> reused as h2 (GEMM1 out);
  //           bufA: h0, dead after combine -> h3 (GEMM2 out);
  //           bufB: h1 (GEMM1 in).
  unsigned short* xh   = (unsigned short*)d_ws;
  unsigned short* bufA = xh + MP * 256;
  unsigned short* bufB = bufA + MP * 256;
  unsigned short* Wt1  = bufB + MP * 256;
  unsigned short* Wt2  = Wt1 + 256 * 256;
  float* stats = (float*)(Wt2 + 256 * 256);         // sum|sumsq|scale|shift

  x2bf_kernel<<<(N * 32 + 255) / 256, 256, 0, stream>>>(x, xh, N * 32);
  prep_kernel<<<256, 256, 0, stream>>>(W1, W2, Wt1, Wt2, stats);
  aggregate_kernel<<<(N + 3) / 4, 256, 0, stream>>>(xh, nbr, bufA, N);
  combine_kernel<<<(N + 3) / 4, 256, 0, stream>>>(bufA, nbr, xh, alpha_p, eps_p, bufB, N);

  dim3 ggrid((unsigned)((N + 127) / 128), 2);
  gemm_relu_kernel<0><<<ggrid, 256, 0, stream>>>(bufB, Wt1, b1, xh, nullptr, N);
  gemm_relu_kernel<1><<<ggrid, 256, 0, stream>>>(xh, Wt2, b2, bufA, stats, N);

  bn_finalize_kernel<<<1, 256, 0, stream>>>(gamma, beta, stats, N);
  bn_norm_kernel<<<(N * 64 + 255) / 256, 256, 0, stream>>>(bufA, stats, out, N * 64);
}

// Round 3
// 444.333 us; speedup vs baseline: 1.2469x; 1.1431x over previous
//
#include <hip/hip_runtime.h>

typedef __bf16 bf16x8 __attribute__((ext_vector_type(8)));
typedef float  f32x4  __attribute__((ext_vector_type(4)));

__device__ __forceinline__ unsigned short f2bf(float f) {
  unsigned u = __builtin_bit_cast(unsigned, f);
  u += 0x7FFFu + ((u >> 16) & 1u);          // round-to-nearest-even
  return (unsigned short)(u >> 16);
}
__device__ __forceinline__ float bf2f(unsigned short b) {
  unsigned u = ((unsigned)b) << 16;
  return __builtin_bit_cast(float, u);
}
__device__ __forceinline__ unsigned pack2bf(float lo, float hi) {
  return (unsigned)f2bf(lo) | ((unsigned)f2bf(hi) << 16);
}

__device__ __forceinline__ void gload_lds16(const void* g, void* l) {
  __builtin_amdgcn_global_load_lds(
      (const __attribute__((address_space(1))) unsigned int*)g,
      (__attribute__((address_space(3))) unsigned int*)l, 16, 0, 0);
}

// ---------------- x -> bf16 copy (gather source) ----------------------------
__global__ __launch_bounds__(256) void x2bf_kernel(
    const float* __restrict__ x, unsigned short* __restrict__ xh, int total8)
{
  const int i = blockIdx.x * 256 + threadIdx.x;
  if (i >= total8) return;
  const float4* p = (const float4*)x + (long)i * 2;
  float4 a = p[0], b = p[1];
  uint4 o;
  o.x = pack2bf(a.x, a.y); o.y = pack2bf(a.z, a.w);
  o.z = pack2bf(b.x, b.y); o.w = pack2bf(b.z, b.w);
  ((uint4*)xh)[i] = o;
}

// ---------------- prep: W -> Wt (transposed bf16), zero stats ----------------
__global__ __launch_bounds__(256) void prep_kernel(
    const float* __restrict__ W1, const float* __restrict__ W2,
    unsigned short* __restrict__ Wt1, unsigned short* __restrict__ Wt2,
    float* __restrict__ stats)
{
  const int n = blockIdx.x;    // output row (original column)
  const int k = threadIdx.x;
  Wt1[n * 256 + k] = f2bf(W1[k * 256 + n]);
  Wt2[n * 256 + k] = f2bf(W2[k * 256 + n]);
  if (n == 0) { stats[k] = 0.f; stats[256 + k] = 0.f; }
}

// ------- aggregate: h0 = mean over neighbors of xh (bf16) -------------------
// 1 wave/node; 16B/lane gathers: half-wave h covers neighbors j=2t+h.
__global__ __launch_bounds__(256) void aggregate_kernel(
    const unsigned short* __restrict__ xh, const int* __restrict__ nbr,
    unsigned short* __restrict__ h0, int N)
{
  const int wid  = (blockIdx.x * 256 + threadIdx.x) >> 6;
  const int lane = threadIdx.x & 63;
  if (wid >= N) return;
  const int half = lane >> 5;
  const int l    = lane & 31;
  const int* nb = nbr + (long)wid * 16;

  int   idx[8];
  float w[8];
#pragma unroll
  for (int t = 0; t < 8; ++t) {
    int v = nb[2 * t + half];
    w[t]   = (v >= 0) ? 1.0f : 0.0f;
    idx[t] = (v >= 0) ? v : 0;
  }
  uint4 vals[8];
#pragma unroll
  for (int t = 0; t < 8; ++t)
    vals[t] = ((const uint4*)(xh + (long)idx[t] * 256))[l];

  float s[8] = {0.f, 0.f, 0.f, 0.f, 0.f, 0.f, 0.f, 0.f};
  float cnt = 0.f;
#pragma unroll
  for (int t = 0; t < 8; ++t) {
    const unsigned short* u = (const unsigned short*)&vals[t];
    cnt += w[t];
#pragma unroll
    for (int e = 0; e < 8; ++e) s[e] = fmaf(w[t], bf2f(u[e]), s[e]);
  }
  // combine the two half-wave partials (same elems, complementary neighbors)
#pragma unroll
  for (int e = 0; e < 8; ++e) s[e] += __shfl_xor(s[e], 32);
  cnt += __shfl_xor(cnt, 32);
  const float inv = cnt > 0.f ? 1.0f / cnt : 0.f;
  if (half == 0) {
    uint4 o;
    o.x = pack2bf(s[0] * inv, s[1] * inv);
    o.y = pack2bf(s[2] * inv, s[3] * inv);
    o.z = pack2bf(s[4] * inv, s[5] * inv);
    o.w = pack2bf(s[6] * inv, s[7] * inv);
    ((uint4*)(h0 + (long)wid * 256))[l] = o;
  }
}

// ------- combine: h1 = h0 + alpha*maxpool(h0, nbrs) + (1+eps)*x -------------
__global__ __launch_bounds__(256) void combine_kernel(
    const unsigned short* __restrict__ h0, const int* __restrict__ nbr,
    const unsigned short* __restrict__ xh, const float* __restrict__ alpha_p,
    const float* __restrict__ eps_p, unsigned short* __restrict__ h1, int N)
{
  const int wid  = (blockIdx.x * 256 + threadIdx.x) >> 6;
  const int lane = threadIdx.x & 63;
  if (wid >= N) return;
  const int half = lane >> 5;
  const int l    = lane & 31;
  const float alpha = *alpha_p;
  const float c     = 1.0f + *eps_p;
  const int* nb = nbr + (long)wid * 16;

  int   idx[8];
  float w[8];
#pragma unroll
  for (int t = 0; t < 8; ++t) {
    int v = nb[2 * t + half];
    w[t]   = (v >= 0) ? 1.0f : 0.0f;
    idx[t] = (v >= 0) ? v : 0;
  }
  // own-row streaming loads issued early (uniform across halves)
  uint4 own = ((const uint4*)(h0 + (long)wid * 256))[l];
  uint4 xv  = ((const uint4*)(xh + (long)wid * 256))[l];
  uint4 vals[8];
#pragma unroll
  for (int t = 0; t < 8; ++t)
    vals[t] = ((const uint4*)(h0 + (long)idx[t] * 256))[l];

  float mx[8];
#pragma unroll
  for (int e = 0; e < 8; ++e) mx[e] = -3.402823466e38f;
#pragma unroll
  for (int t = 0; t < 8; ++t) {
    const unsigned short* u = (const unsigned short*)&vals[t];
    const bool valid = w[t] > 0.f;
#pragma unroll
    for (int e = 0; e < 8; ++e) {
      float vv = valid ? bf2f(u[e]) : -3.402823466e38f;
      mx[e] = fmaxf(mx[e], vv);
    }
  }
#pragma unroll
  for (int e = 0; e < 8; ++e) mx[e] = fmaxf(mx[e], __shfl_xor(mx[e], 32));

  if (half == 0) {
    const unsigned short* uo = (const unsigned short*)&own;
    const unsigned short* ux = (const unsigned short*)&xv;
    float r[8];
#pragma unroll
    for (int e = 0; e < 8; ++e)
      r[e] = bf2f(uo[e]) + alpha * mx[e] + c * bf2f(ux[e]);
    uint4 o;
    o.x = pack2bf(r[0], r[1]); o.y = pack2bf(r[2], r[3]);
    o.z = pack2bf(r[4], r[5]); o.w = pack2bf(r[6], r[7]);
    ((uint4*)(h1 + (long)wid * 256))[l] = o;
  }
}

// ---------------- GEMM + bias + relu (+ optional BN stats) ------------------
// C[M][256] = relu(A[M][256] @ W[256][256] + b); A bf16, Wt = W^T bf16 [n][k].
// 128x128 tile, BK=32, 4 waves (2x2), 16x16x32 bf16 MFMA.
template<int WITH_STATS>
__global__ __launch_bounds__(256, 2) void gemm_relu_kernel(
    const unsigned short* __restrict__ A, const unsigned short* __restrict__ Wt,
    const float* __restrict__ bias, unsigned short* __restrict__ Out,
    float* __restrict__ stats, int M)
{
  __shared__ __align__(16) unsigned short lA[128 * 32];
  __shared__ __align__(16) unsigned short lB[128 * 32];
  const int tid  = threadIdx.x;
  const int lane = tid & 63;
  const int wave = tid >> 6;
  const int wm = wave >> 1, wn = wave & 1;
  const int g = lane >> 4, lr = lane & 15;
  const long row0 = (long)blockIdx.x * 128;
  const int  col0 = blockIdx.y * 128;

  f32x4 acc[4][4] = {};

  const int o0 = tid * 16;
  const int o1 = (256 + tid) * 16;
  const int ra = o0 >> 6, ca = o0 & 63;
  const int rb = o1 >> 6, cb = o1 & 63;
  const char* Ab = (const char*)A;
  const char* Bb = (const char*)Wt;
  char* lAc = (char*)lA;
  char* lBc = (char*)lB;

  for (int kk = 0; kk < 8; ++kk) {
    const int kb = kk * 64;   // byte offset in K
    gload_lds16(Ab + (row0 + ra) * 512 + kb + ca, lAc + wave * 1024);
    gload_lds16(Ab + (row0 + rb) * 512 + kb + cb, lAc + 4096 + wave * 1024);
    gload_lds16(Bb + (long)(col0 + ra) * 512 + kb + ca, lBc + wave * 1024);
    gload_lds16(Bb + (long)(col0 + rb) * 512 + kb + cb, lBc + 4096 + wave * 1024);
    __syncthreads();
    bf16x8 af[4], bq[4];
#pragma unroll
    for (int mt = 0; mt < 4; ++mt)
      af[mt] = *(const bf16x8*)&lA[(wm * 64 + mt * 16 + lr) * 32 + 8 * g];
#pragma unroll
    for (int nt = 0; nt < 4; ++nt)
      bq[nt] = *(const bf16x8*)&lB[(wn * 64 + nt * 16 + lr) * 32 + 8 * g];
#pragma unroll
    for (int mt = 0; mt < 4; ++mt)
#pragma unroll
      for (int nt = 0; nt < 4; ++nt)
        acc[mt][nt] = __builtin_amdgcn_mfma_f32_16x16x32_bf16(
            af[mt], bq[nt], acc[mt][nt], 0, 0, 0);
    __syncthreads();
  }

#pragma unroll
  for (int nt = 0; nt < 4; ++nt) {
    const int col = col0 + wn * 64 + nt * 16 + lr;
    const float bv = bias[col];
    float s = 0.f, s2 = 0.f;
#pragma unroll
    for (int mt = 0; mt < 4; ++mt) {
      const long rbase = row0 + wm * 64 + mt * 16 + g * 4;
      f32x4 v = acc[mt][nt];
#pragma unroll
      for (int r = 0; r < 4; ++r) {
        float val = fmaxf(v[r] + bv, 0.f);
        const long row = rbase + r;
        if (row < M) {
          Out[row * 256 + col] = f2bf(val);
          if (WITH_STATS) { s += val; s2 += val * val; }
        }
      }
    }
    if (WITH_STATS) {
      s  += __shfl_xor(s, 16);  s2 += __shfl_xor(s2, 16);
      s  += __shfl_xor(s, 32);  s2 += __shfl_xor(s2, 32);
      if (g == 0) {
        atomicAdd(&stats[col], s);
        atomicAdd(&stats[256 + col], s2);
      }
    }
  }
}

// ---------------- BN finalize: scale/shift per column -----------------------
__global__ __launch_bounds__(256) void bn_finalize_kernel(
    const float* __restrict__ gamma, const float* __restrict__ beta,
    float* __restrict__ stats, int M)
{
  const int n = threadIdx.x;
  const float invM = 1.0f / (float)M;
  const float mean = stats[n] * invM;
  float var = stats[256 + n] * invM - mean * mean;
  var = fmaxf(var, 0.f);
  const float sc = gamma[n] * rsqrtf(var + 1e-5f);
  stats[512 + n] = sc;
  stats[768 + n] = beta[n] - mean * sc;
}

// ---------------- BN normalize: out = h3*scale + shift (8 elems/thread) -----
__global__ __launch_bounds__(256) void bn_norm_kernel(
    const unsigned short* __restrict__ h3, const float* __restrict__ stats,
    float* __restrict__ out, int total8)
{
  const int i = blockIdx.x * 256 + threadIdx.x;
  if (i >= total8) return;
  uint4 v = ((const uint4*)h3)[i];
  const int c = (i * 8) & 255;
  const float4 sc0 = *(const float4*)&stats[512 + c];
  const float4 sc1 = *(const float4*)&stats[516 + c];
  const float4 sh0 = *(const float4*)&stats[768 + c];
  const float4 sh1 = *(const float4*)&stats[772 + c];
  const unsigned short* u = (const unsigned short*)&v;
  float4 o0, o1;
  o0.x = bf2f(u[0]) * sc0.x + sh0.x;
  o0.y = bf2f(u[1]) * sc0.y + sh0.y;
  o0.z = bf2f(u[2]) * sc0.z + sh0.z;
  o0.w = bf2f(u[3]) * sc0.w + sh0.w;
  o1.x = bf2f(u[4]) * sc1.x + sh1.x;
  o1.y = bf2f(u[5]) * sc1.y + sh1.y;
  o1.z = bf2f(u[6]) * sc1.z + sh1.z;
  o1.w = bf2f(u[7]) * sc1.w + sh1.w;
  ((float4*)out)[2 * i]     = o0;
  ((float4*)out)[2 * i + 1] = o1;
}

// ----------------------------------------------------------------------------
extern "C" void kernel_launch(void* const* d_in, const int* in_sizes, int n_in,
                              void* d_out, int out_size, void* d_ws, size_t ws_size,
                              hipStream_t stream) {
  const float* x     = (const float*)d_in[0];
  const int*   nbr   = (const int*)d_in[1];
  const float* W1    = (const float*)d_in[2];
  const float* b1    = (const float*)d_in[3];
  const float* W2    = (const float*)d_in[4];
  const float* b2    = (const float*)d_in[5];
  const float* gamma = (const float*)d_in[6];
  const float* beta  = (const float*)d_in[7];
  const float* alpha_p = (const float*)d_in[8];
  const float* eps_p   = (const float*)d_in[9];
  float* out = (float*)d_out;

  const int  N  = in_sizes[0] / 256;            // 100000
  const long MP = ((long)N + 127) & ~127L;      // padded rows for GEMM tiles

  // ws layout: xh | bufA | bufB | Wt1 | Wt2 | stats
  // lifetime: xh dead after combine -> h2 (GEMM1 out); bufA: h0 -> h3.
  unsigned short* xh   = (unsigned short*)d_ws;
  unsigned short* bufA = xh + MP * 256;
  unsigned short* bufB = bufA + MP * 256;
  unsigned short* Wt1  = bufB + MP * 256;
  unsigned short* Wt2  = Wt1 + 256 * 256;
  float* stats = (float*)(Wt2 + 256 * 256);         // sum|sumsq|scale|shift

  x2bf_kernel<<<(N * 32 + 255) / 256, 256, 0, stream>>>(x, xh, N * 32);
  prep_kernel<<<256, 256, 0, stream>>>(W1, W2, Wt1, Wt2, stats);
  aggregate_kernel<<<(N + 3) / 4, 256, 0, stream>>>(xh, nbr, bufA, N);
  combine_kernel<<<(N + 3) / 4, 256, 0, stream>>>(bufA, nbr, xh, alpha_p, eps_p, bufB, N);

  dim3 ggrid((unsigned)((N + 127) / 128), 2);
  gemm_relu_kernel<0><<<ggrid, 256, 0, stream>>>(bufB, Wt1, b1, xh, nullptr, N);
  gemm_relu_kernel<1><<<ggrid, 256, 0, stream>>>(xh, Wt2, b2, bufA, stats, N);

  bn_finalize_kernel<<<1, 256, 0, stream>>>(gamma, beta, stats, N);
  bn_norm_kernel<<<(N * 32 + 255) / 256, 256, 0, stream>>>(bufA, stats, out, N * 32);
}

// Round 4
// 406.072 us; speedup vs baseline: 1.3644x; 1.0942x over previous
//
#include <hip/hip_runtime.h>

typedef __bf16 bf16x8 __attribute__((ext_vector_type(8)));
typedef float  f32x4  __attribute__((ext_vector_type(4)));

__device__ __forceinline__ unsigned short f2bf(float f) {
  unsigned u = __builtin_bit_cast(unsigned, f);
  u += 0x7FFFu + ((u >> 16) & 1u);          // round-to-nearest-even
  return (unsigned short)(u >> 16);
}
__device__ __forceinline__ float bf2f(unsigned short b) {
  unsigned u = ((unsigned)b) << 16;
  return __builtin_bit_cast(float, u);
}
__device__ __forceinline__ float bflo(unsigned q) {        // low bf16 of word
  return __builtin_bit_cast(float, q << 16);
}
__device__ __forceinline__ float bfhi(unsigned q) {        // high bf16 of word
  return __builtin_bit_cast(float, q & 0xFFFF0000u);
}
__device__ __forceinline__ unsigned pack2bf(float lo, float hi) {
  return (unsigned)f2bf(lo) | ((unsigned)f2bf(hi) << 16);
}

__device__ __forceinline__ void gload_lds16(const void* g, void* l) {
  __builtin_amdgcn_global_load_lds(
      (const __attribute__((address_space(1))) unsigned int*)g,
      (__attribute__((address_space(3))) unsigned int*)l, 16, 0, 0);
}

// ---------------- x -> bf16 copy (gather source) ----------------------------
__global__ __launch_bounds__(256) void x2bf_kernel(
    const float* __restrict__ x, unsigned short* __restrict__ xh, int total8)
{
  const int i = blockIdx.x * 256 + threadIdx.x;
  if (i >= total8) return;
  const float4* p = (const float4*)x + (long)i * 2;
  float4 a = p[0], b = p[1];
  uint4 o;
  o.x = pack2bf(a.x, a.y); o.y = pack2bf(a.z, a.w);
  o.z = pack2bf(b.x, b.y); o.w = pack2bf(b.z, b.w);
  ((uint4*)xh)[i] = o;
}

// ---------------- prep: W -> Wt (transposed bf16), zero stats ----------------
__global__ __launch_bounds__(256) void prep_kernel(
    const float* __restrict__ W1, const float* __restrict__ W2,
    unsigned short* __restrict__ Wt1, unsigned short* __restrict__ Wt2,
    float* __restrict__ stats)
{
  const int n = blockIdx.x;    // output row (original column)
  const int k = threadIdx.x;
  Wt1[n * 256 + k] = f2bf(W1[k * 256 + n]);
  Wt2[n * 256 + k] = f2bf(W2[k * 256 + n]);
  if (n == 0) { stats[k] = 0.f; stats[256 + k] = 0.f; }
}

// ------- aggregate: h0 = mean over neighbors of xh (bf16) -------------------
// 1 wave/node; half-wave h handles neighbors 8h..8h+7, 16B/lane gathers.
__global__ __launch_bounds__(256) void aggregate_kernel(
    const unsigned short* __restrict__ xh, const int* __restrict__ nbr,
    unsigned short* __restrict__ h0, int N)
{
  const int wid  = (blockIdx.x * 256 + threadIdx.x) >> 6;
  const int lane = threadIdx.x & 63;
  if (wid >= N) return;
  const int half = lane >> 5;
  const int l    = lane & 31;
  const int* nb = nbr + (long)wid * 16;
  int4 n0 = ((const int4*)nb)[half * 2];
  int4 n1 = ((const int4*)nb)[half * 2 + 1];
  int v[8] = {n0.x, n0.y, n0.z, n0.w, n1.x, n1.y, n1.z, n1.w};
  int mn = v[0];
#pragma unroll
  for (int t = 1; t < 8; ++t) mn = min(mn, v[t]);

  if (__all(mn >= 0)) {                       // fast path: all 16 valid
    uint4 vals[8];
#pragma unroll
    for (int t = 0; t < 8; ++t)
      vals[t] = ((const uint4*)(xh + (long)v[t] * 256))[l];
    float sl[4] = {0.f, 0.f, 0.f, 0.f}, sh[4] = {0.f, 0.f, 0.f, 0.f};
#pragma unroll
    for (int t = 0; t < 8; ++t) {
      const unsigned* q = (const unsigned*)&vals[t];
#pragma unroll
      for (int w = 0; w < 4; ++w) { sl[w] += bflo(q[w]); sh[w] += bfhi(q[w]); }
    }
#pragma unroll
    for (int w = 0; w < 4; ++w) {
      sl[w] += __shfl_xor(sl[w], 32);
      sh[w] += __shfl_xor(sh[w], 32);
    }
    if (half == 0) {
      uint4 o;
      unsigned* q = (unsigned*)&o;
#pragma unroll
      for (int w = 0; w < 4; ++w) q[w] = pack2bf(sl[w] * 0.0625f, sh[w] * 0.0625f);
      ((uint4*)(h0 + (long)wid * 256))[l] = o;
    }
    return;
  }
  // slow path: masked mean
  float wgt[8]; int idx[8];
#pragma unroll
  for (int t = 0; t < 8; ++t) {
    wgt[t] = (v[t] >= 0) ? 1.0f : 0.0f;
    idx[t] = (v[t] >= 0) ? v[t] : 0;
  }
  uint4 vals[8];
#pragma unroll
  for (int t = 0; t < 8; ++t)
    vals[t] = ((const uint4*)(xh + (long)idx[t] * 256))[l];
  float s[8] = {0.f,0.f,0.f,0.f,0.f,0.f,0.f,0.f};
  float cnt = 0.f;
#pragma unroll
  for (int t = 0; t < 8; ++t) {
    const unsigned short* u = (const unsigned short*)&vals[t];
    cnt += wgt[t];
#pragma unroll
    for (int e = 0; e < 8; ++e) s[e] = fmaf(wgt[t], bf2f(u[e]), s[e]);
  }
#pragma unroll
  for (int e = 0; e < 8; ++e) s[e] += __shfl_xor(s[e], 32);
  cnt += __shfl_xor(cnt, 32);
  const float inv = cnt > 0.f ? 1.0f / cnt : 0.f;
  if (half == 0) {
    uint4 o;
    o.x = pack2bf(s[0] * inv, s[1] * inv);
    o.y = pack2bf(s[2] * inv, s[3] * inv);
    o.z = pack2bf(s[4] * inv, s[5] * inv);
    o.w = pack2bf(s[6] * inv, s[7] * inv);
    ((uint4*)(h0 + (long)wid * 256))[l] = o;
  }
}

// ------- combine: h1 = h0 + alpha*maxpool(h0, nbrs) + (1+eps)*x -------------
__global__ __launch_bounds__(256) void combine_kernel(
    const unsigned short* __restrict__ h0, const int* __restrict__ nbr,
    const unsigned short* __restrict__ xh, const float* __restrict__ alpha_p,
    const float* __restrict__ eps_p, unsigned short* __restrict__ h1, int N)
{
  const int wid  = (blockIdx.x * 256 + threadIdx.x) >> 6;
  const int lane = threadIdx.x & 63;
  if (wid >= N) return;
  const int half = lane >> 5;
  const int l    = lane & 31;
  const float alpha = *alpha_p;
  const float c     = 1.0f + *eps_p;
  const int* nb = nbr + (long)wid * 16;
  int4 n0 = ((const int4*)nb)[half * 2];
  int4 n1 = ((const int4*)nb)[half * 2 + 1];
  int v[8] = {n0.x, n0.y, n0.z, n0.w, n1.x, n1.y, n1.z, n1.w};
  int mn = v[0];
#pragma unroll
  for (int t = 1; t < 8; ++t) mn = min(mn, v[t]);

  // own-row streaming loads issued early
  uint4 own = ((const uint4*)(h0 + (long)wid * 256))[l];
  uint4 xv  = ((const uint4*)(xh + (long)wid * 256))[l];

  if (__all(mn >= 0)) {                       // fast path: all 16 valid
    uint4 vals[8];
#pragma unroll
    for (int t = 0; t < 8; ++t)
      vals[t] = ((const uint4*)(h0 + (long)v[t] * 256))[l];
    float ml[4], mh[4];
#pragma unroll
    for (int w = 0; w < 4; ++w) { ml[w] = -3.402823466e38f; mh[w] = -3.402823466e38f; }
#pragma unroll
    for (int t = 0; t < 8; ++t) {
      const unsigned* q = (const unsigned*)&vals[t];
#pragma unroll
      for (int w = 0; w < 4; ++w) {
        ml[w] = fmaxf(ml[w], bflo(q[w]));
        mh[w] = fmaxf(mh[w], bfhi(q[w]));
      }
    }
#pragma unroll
    for (int w = 0; w < 4; ++w) {
      ml[w] = fmaxf(ml[w], __shfl_xor(ml[w], 32));
      mh[w] = fmaxf(mh[w], __shfl_xor(mh[w], 32));
    }
    if (half == 0) {
      const unsigned* qo = (const unsigned*)&own;
      const unsigned* qx = (const unsigned*)&xv;
      uint4 o;
      unsigned* q = (unsigned*)&o;
#pragma unroll
      for (int w = 0; w < 4; ++w) {
        float rl = bflo(qo[w]) + alpha * ml[w] + c * bflo(qx[w]);
        float rh = bfhi(qo[w]) + alpha * mh[w] + c * bfhi(qx[w]);
        q[w] = pack2bf(rl, rh);
      }
      ((uint4*)(h1 + (long)wid * 256))[l] = o;
    }
    return;
  }
  // slow path: masked max
  float wgt[8]; int idx[8];
#pragma unroll
  for (int t = 0; t < 8; ++t) {
    wgt[t] = (v[t] >= 0) ? 1.0f : 0.0f;
    idx[t] = (v[t] >= 0) ? v[t] : 0;
  }
  uint4 vals[8];
#pragma unroll
  for (int t = 0; t < 8; ++t)
    vals[t] = ((const uint4*)(h0 + (long)idx[t] * 256))[l];
  float mx[8];
#pragma unroll
  for (int e = 0; e < 8; ++e) mx[e] = -3.402823466e38f;
#pragma unroll
  for (int t = 0; t < 8; ++t) {
    const unsigned short* u = (const unsigned short*)&vals[t];
    const bool valid = wgt[t] > 0.f;
#pragma unroll
    for (int e = 0; e < 8; ++e) {
      float vv = valid ? bf2f(u[e]) : -3.402823466e38f;
      mx[e] = fmaxf(mx[e], vv);
    }
  }
#pragma unroll
  for (int e = 0; e < 8; ++e) mx[e] = fmaxf(mx[e], __shfl_xor(mx[e], 32));
  if (half == 0) {
    const unsigned short* uo = (const unsigned short*)&own;
    const unsigned short* ux = (const unsigned short*)&xv;
    float r[8];
#pragma unroll
    for (int e = 0; e < 8; ++e)
      r[e] = bf2f(uo[e]) + alpha * mx[e] + c * bf2f(ux[e]);
    uint4 o;
    o.x = pack2bf(r[0], r[1]); o.y = pack2bf(r[2], r[3]);
    o.z = pack2bf(r[4], r[5]); o.w = pack2bf(r[6], r[7]);
    ((uint4*)(h1 + (long)wid * 256))[l] = o;
  }
}

// ---------------- fused MLP: out = relu(relu(A@W1+b1)@W2+b2), + BN stats ----
// 128 rows/block, 8 waves (wm = wave>>2 picks row-half, wn = wave&3 col-quarter).
// Stage 1: A (global) @ W1 -> h2 in LDS (XOR-swizzled). Stage 2: h2 @ W2 -> out.
__global__ __launch_bounds__(512, 1) void mlp_kernel(
    const unsigned short* __restrict__ A, const unsigned short* __restrict__ W1t,
    const float* __restrict__ b1, const unsigned short* __restrict__ W2t,
    const float* __restrict__ b2, unsigned short* __restrict__ Out,
    float* __restrict__ stats, int M)
{
  __shared__ __align__(16) unsigned short lA[128 * 32];    //  8 KB
  __shared__ __align__(16) unsigned short lW[256 * 32];    // 16 KB
  __shared__ __align__(16) unsigned short lH[128 * 256];   // 64 KB
  const int tid  = threadIdx.x;
  const int lane = tid & 63;
  const int wave = tid >> 6;
  const int wm = wave >> 2, wn = wave & 3;
  const int g = lane >> 4, lr = lane & 15;
  const long row0 = (long)blockIdx.x * 128;

  f32x4 acc[4][4] = {};
  const int arow = tid >> 2, acol = (tid & 3) * 16;   // 512 thr x 16B staging
  const char* Ab  = (const char*)A;
  const char* W1b = (const char*)W1t;
  const char* W2b = (const char*)W2t;
  char* lAc = (char*)lA;
  char* lWc = (char*)lW;
  char* lHc = (char*)lH;

  // ---- stage 1: h2 = relu(A @ W1 + b1) ----
  for (int kk = 0; kk < 8; ++kk) {
    const int kb = kk * 64;
    gload_lds16(Ab + (row0 + arow) * 512 + kb + acol, lAc + tid * 16);
    gload_lds16(W1b + (long)arow * 512 + kb + acol, lWc + tid * 16);
    gload_lds16(W1b + (long)(128 + arow) * 512 + kb + acol, lWc + 8192 + tid * 16);
    __syncthreads();
    bf16x8 af[4], bq[4];
#pragma unroll
    for (int mt = 0; mt < 4; ++mt)
      af[mt] = *(const bf16x8*)&lA[(wm * 64 + mt * 16 + lr) * 32 + 8 * g];
#pragma unroll
    for (int nt = 0; nt < 4; ++nt)
      bq[nt] = *(const bf16x8*)&lW[(wn * 64 + nt * 16 + lr) * 32 + 8 * g];
#pragma unroll
    for (int mt = 0; mt < 4; ++mt)
#pragma unroll
      for (int nt = 0; nt < 4; ++nt)
        acc[mt][nt] = __builtin_amdgcn_mfma_f32_16x16x32_bf16(
            af[mt], bq[nt], acc[mt][nt], 0, 0, 0);
    __syncthreads();
  }
  // h2 -> LDS (bias + relu), XOR-swizzled rows
#pragma unroll
  for (int nt = 0; nt < 4; ++nt) {
    const int col = wn * 64 + nt * 16 + lr;
    const float bv = b1[col];
#pragma unroll
    for (int mt = 0; mt < 4; ++mt) {
      f32x4 vv = acc[mt][nt];
#pragma unroll
      for (int e = 0; e < 4; ++e) {
        const int row = wm * 64 + mt * 16 + 4 * g + e;
        const int byte = (row * 512 + col * 2) ^ ((row & 7) << 4);
        *(unsigned short*)(lHc + byte) = f2bf(fmaxf(vv[e] + bv, 0.f));
      }
    }
  }
#pragma unroll
  for (int mt = 0; mt < 4; ++mt)
#pragma unroll
    for (int nt = 0; nt < 4; ++nt)
      acc[mt][nt] = (f32x4){0.f, 0.f, 0.f, 0.f};
  __syncthreads();

  // ---- stage 2: out = relu(h2 @ W2 + b2) ----
  for (int kk = 0; kk < 8; ++kk) {
    const int kb = kk * 64;
    gload_lds16(W2b + (long)arow * 512 + kb + acol, lWc + tid * 16);
    gload_lds16(W2b + (long)(128 + arow) * 512 + kb + acol, lWc + 8192 + tid * 16);
    __syncthreads();
    bf16x8 af[4], bq[4];
#pragma unroll
    for (int mt = 0; mt < 4; ++mt) {
      const int row = wm * 64 + mt * 16 + lr;
      af[mt] = *(const bf16x8*)(lHc + ((row * 512 + kb + 16 * g) ^ ((row & 7) << 4)));
    }
#pragma unroll
    for (int nt = 0; nt < 4; ++nt)
      bq[nt] = *(const bf16x8*)&lW[(wn * 64 + nt * 16 + lr) * 32 + 8 * g];
#pragma unroll
    for (int mt = 0; mt < 4; ++mt)
#pragma unroll
      for (int nt = 0; nt < 4; ++nt)
        acc[mt][nt] = __builtin_amdgcn_mfma_f32_16x16x32_bf16(
            af[mt], bq[nt], acc[mt][nt], 0, 0, 0);
    __syncthreads();
  }

  // ---- epilogue: bias + relu + store + BN stats ----
#pragma unroll
  for (int nt = 0; nt < 4; ++nt) {
    const int col = wn * 64 + nt * 16 + lr;
    const float bv = b2[col];
    float s = 0.f, s2 = 0.f;
#pragma unroll
    for (int mt = 0; mt < 4; ++mt) {
      f32x4 vv = acc[mt][nt];
#pragma unroll
      for (int e = 0; e < 4; ++e) {
        const long row = row0 + wm * 64 + mt * 16 + 4 * g + e;
        float val = fmaxf(vv[e] + bv, 0.f);
        if (row < M) {
          Out[row * 256 + col] = f2bf(val);
          s += val; s2 += val * val;
        }
      }
    }
    s  += __shfl_xor(s, 16);  s2 += __shfl_xor(s2, 16);
    s  += __shfl_xor(s, 32);  s2 += __shfl_xor(s2, 32);
    if (g == 0) {
      atomicAdd(&stats[col], s);
      atomicAdd(&stats[256 + col], s2);
    }
  }
}

// ---------------- BN finalize: scale/shift per column -----------------------
__global__ __launch_bounds__(256) void bn_finalize_kernel(
    const float* __restrict__ gamma, const float* __restrict__ beta,
    float* __restrict__ stats, int M)
{
  const int n = threadIdx.x;
  const float invM = 1.0f / (float)M;
  const float mean = stats[n] * invM;
  float var = stats[256 + n] * invM - mean * mean;
  var = fmaxf(var, 0.f);
  const float sc = gamma[n] * rsqrtf(var + 1e-5f);
  stats[512 + n] = sc;
  stats[768 + n] = beta[n] - mean * sc;
}

// ---------------- BN normalize: out = h3*scale + shift (8 elems/thread) -----
__global__ __launch_bounds__(256) void bn_norm_kernel(
    const unsigned short* __restrict__ h3, const float* __restrict__ stats,
    float* __restrict__ out, int total8)
{
  const int i = blockIdx.x * 256 + threadIdx.x;
  if (i >= total8) return;
  uint4 v = ((const uint4*)h3)[i];
  const int c = (i * 8) & 255;
  const float4 sc0 = *(const float4*)&stats[512 + c];
  const float4 sc1 = *(const float4*)&stats[516 + c];
  const float4 sh0 = *(const float4*)&stats[768 + c];
  const float4 sh1 = *(const float4*)&stats[772 + c];
  const unsigned short* u = (const unsigned short*)&v;
  float4 o0, o1;
  o0.x = bf2f(u[0]) * sc0.x + sh0.x;
  o0.y = bf2f(u[1]) * sc0.y + sh0.y;
  o0.z = bf2f(u[2]) * sc0.z + sh0.z;
  o0.w = bf2f(u[3]) * sc0.w + sh0.w;
  o1.x = bf2f(u[4]) * sc1.x + sh1.x;
  o1.y = bf2f(u[5]) * sc1.y + sh1.y;
  o1.z = bf2f(u[6]) * sc1.z + sh1.z;
  o1.w = bf2f(u[7]) * sc1.w + sh1.w;
  ((float4*)out)[2 * i]     = o0;
  ((float4*)out)[2 * i + 1] = o1;
}

// ----------------------------------------------------------------------------
extern "C" void kernel_launch(void* const* d_in, const int* in_sizes, int n_in,
                              void* d_out, int out_size, void* d_ws, size_t ws_size,
                              hipStream_t stream) {
  const float* x     = (const float*)d_in[0];
  const int*   nbr   = (const int*)d_in[1];
  const float* W1    = (const float*)d_in[2];
  const float* b1    = (const float*)d_in[3];
  const float* W2    = (const float*)d_in[4];
  const float* b2    = (const float*)d_in[5];
  const float* gamma = (const float*)d_in[6];
  const float* beta  = (const float*)d_in[7];
  const float* alpha_p = (const float*)d_in[8];
  const float* eps_p   = (const float*)d_in[9];
  float* out = (float*)d_out;

  const int  N  = in_sizes[0] / 256;            // 100000
  const long MP = ((long)N + 127) & ~127L;      // padded rows (100096 = 782*128)

  // ws layout: xh | bufA (h0 -> mlp out) | bufB (h1) | Wt1 | Wt2 | stats
  unsigned short* xh   = (unsigned short*)d_ws;
  unsigned short* bufA = xh + MP * 256;
  unsigned short* bufB = bufA + MP * 256;
  unsigned short* Wt1  = bufB + MP * 256;
  unsigned short* Wt2  = Wt1 + 256 * 256;
  float* stats = (float*)(Wt2 + 256 * 256);     // sum|sumsq|scale|shift

  x2bf_kernel<<<(N * 32 + 255) / 256, 256, 0, stream>>>(x, xh, N * 32);
  prep_kernel<<<256, 256, 0, stream>>>(W1, W2, Wt1, Wt2, stats);
  aggregate_kernel<<<(N + 3) / 4, 256, 0, stream>>>(xh, nbr, bufA, N);
  combine_kernel<<<(N + 3) / 4, 256, 0, stream>>>(bufA, nbr, xh, alpha_p, eps_p, bufB, N);

  mlp_kernel<<<(unsigned)(MP / 128), 512, 0, stream>>>(
      bufB, Wt1, b1, Wt2, b2, bufA, stats, N);

  bn_finalize_kernel<<<1, 256, 0, stream>>>(gamma, beta, stats, N);
  bn_norm_kernel<<<(N * 32 + 255) / 256, 256, 0, stream>>>(bufA, stats, out, N * 32);
}